// Round 16
// baseline (2002.893 us; speedup 1.0000x reference)
//
#include <hip/hip_runtime.h>
#include <stdint.h>

#define NN 100000
#define NE 3200000
#define NNZT (NE + NN)
#define DIM 256
#define WCOLS 2048

typedef __bf16 v8bf __attribute__((ext_vector_type(8)));
typedef float f32x4 __attribute__((ext_vector_type(4)));
typedef float f32x2 __attribute__((ext_vector_type(2)));

__device__ __forceinline__ unsigned f2bfu(float f){
  unsigned u = __builtin_bit_cast(unsigned, f);
  return (u + 0x7FFFu + ((u >> 16) & 1u)) >> 16;
}
__device__ __forceinline__ float lrelu(float x){ return fmaxf(x, 0.2f * x); }
__device__ __forceinline__ int imin(int a, int b){ return a < b ? a : b; }
__device__ __forceinline__ unsigned char f2fp8(float f){
  return (unsigned char)(__builtin_amdgcn_cvt_pk_fp8_f32(f, f, 0, false) & 0xff);
}
// packed dual-FP32 FMA: d = a*b + c on 2-wide f32 (VGPR pairs)
__device__ __forceinline__ f32x2 pkfma(f32x2 a, f32x2 b, f32x2 c){
  f32x2 d;
  asm("v_pk_fma_f32 %0, %1, %2, %3" : "=v"(d) : "v"(a), "v"(b), "v"(c));
  return d;
}
// 8 fp8 bytes (uint2) -> v8bf (8 bf16), element order preserved
__device__ __forceinline__ v8bf fp8x8_to_bf16(uint2 raw){
  f32x2 f01 = __builtin_amdgcn_cvt_pk_f32_fp8((int)raw.x, false);
  f32x2 f23 = __builtin_amdgcn_cvt_pk_f32_fp8((int)raw.x, true);
  f32x2 f45 = __builtin_amdgcn_cvt_pk_f32_fp8((int)raw.y, false);
  f32x2 f67 = __builtin_amdgcn_cvt_pk_f32_fp8((int)raw.y, true);
  v8bf r;
  r[0] = (__bf16)f01[0]; r[1] = (__bf16)f01[1];
  r[2] = (__bf16)f23[0]; r[3] = (__bf16)f23[1];
  r[4] = (__bf16)f45[0]; r[5] = (__bf16)f45[1];
  r[6] = (__bf16)f67[0]; r[7] = (__bf16)f67[1];
  return r;
}
// async global -> LDS, 16B per lane; LDS dest is wave-uniform base + lane*16
__device__ __forceinline__ void gl_lds16(const void* g, void* l){
  __builtin_amdgcn_global_load_lds(
      (const __attribute__((address_space(1))) void*)g,
      (__attribute__((address_space(3))) void*)l, 16, 0, 0);
}
__device__ __forceinline__ long long mk64(unsigned lo, unsigned hi){
  return (long long)(((unsigned long long)hi << 32) | lo);
}

// ---- cast x fp32 -> fp8 (4 elems/thread) ----
__global__ void k_cast_x8(const float* __restrict__ x, unsigned char* __restrict__ x8){
  int t = blockIdx.x * 256 + threadIdx.x;           // 6.4M threads exact
  float4 v = ((const float4*)x)[t];
  int lo = __builtin_amdgcn_cvt_pk_fp8_f32(v.x, v.y, 0, false);
  int both = __builtin_amdgcn_cvt_pk_fp8_f32(v.z, v.w, lo, true);
  ((int*)x8)[t] = both;
}

// ---- WaggT8[j][h*256+d] = fp8( W[d][h*256+j] * 8 )  ([256][2048] fp8) ----
__global__ void k_make_waggt8(const float* __restrict__ W, unsigned char* __restrict__ bt8){
  int t = blockIdx.x * 256 + threadIdx.x;           // 524288
  int d = t >> 11, c = t & 2047;                    // W flat index = d*2048 + c
  bt8[(size_t)(c & 255) * WCOLS + (c >> 8) * 256 + d] = f2fp8(W[t] * 8.0f);
}

// ---- Vt[h][k] = sum_d W[k][h*256+d]*a_s[h][d]; Vt[8+h][k] same with a_d (bf16) ----
__global__ void k_make_vt(const float* __restrict__ W, const float* __restrict__ as_,
                          const float* __restrict__ ad_, unsigned short* __restrict__ vt){
  int h = blockIdx.x, k = threadIdx.x;              // 8 x 256
  const float* wr = W + (size_t)k * WCOLS + h * 256;
  const float* a1 = as_ + h * 256;
  const float* a2 = ad_ + h * 256;
  float ss = 0.f, sd = 0.f;
  for (int d = 0; d < 256; ++d){ float wv = wr[d]; ss += wv * a1[d]; sd += wv * a2[d]; }
  vt[h * 256 + k] = (unsigned short)f2bfu(ss);
  vt[(8 + h) * 256 + k] = (unsigned short)f2bfu(sd);
}

// ---- CSR build (structure identical to the round-2/7/10/12/13/14/15 PASSING kernels) ----
__global__ void k_zero_col(int* __restrict__ col){
  int t = blockIdx.x * 256 + threadIdx.x;
  if (t < NNZT) col[t] = 0;
}
__global__ void k_deg_init(int* __restrict__ deg){
  int t = blockIdx.x * 256 + threadIdx.x;
  if (t < NN) deg[t] = 1;                            // self-loop
}
__global__ void k_hist(const int* __restrict__ ei, int* __restrict__ deg){
  int t = blockIdx.x * 256 + threadIdx.x;            // NE threads exact
  int d = ei[NE + t];
  if ((unsigned)d < NN) atomicAdd(&deg[d], 1);
}
__global__ void __launch_bounds__(1024) k_scan(const int* __restrict__ deg,
                                               int* __restrict__ rp, int* cur){
  __shared__ int ps[1024];
  int t = threadIdx.x;
  int lo = t * 98;
  int hi = lo + 98; if (hi > NN) hi = NN; if (lo > NN) lo = NN;
  int s = 0;
  for (int i = lo; i < hi; ++i) s += deg[i];
  ps[t] = s;
  __syncthreads();
  if (t == 0){
    int run = 0;
    for (int i = 0; i < 1024; ++i){ int v = ps[i]; ps[i] = run; run += v; }
    rp[NN] = run;
  }
  __syncthreads();
  int run = ps[t];
  for (int i = lo; i < hi; ++i){
    int dv = deg[i];
    rp[i] = run; cur[i] = run;
    run += dv;
  }
}
__global__ void k_fill_self(int* __restrict__ cur, int* __restrict__ col){
  int t = blockIdx.x * 256 + threadIdx.x;
  if (t < NN){
    int s = atomicAdd(&cur[t], 1);
    if ((unsigned)s < NNZT) col[s] = t;
  }
}
__global__ void k_fill_edge(const int* __restrict__ ei, int* __restrict__ cur, int* __restrict__ col){
  int t = blockIdx.x * 256 + threadIdx.x;
  int s = ei[t], d = ei[NE + t];
  if ((unsigned)d >= NN) return;                     // matches k_hist guard
  if ((unsigned)s >= NN) s = d;
  int slot = atomicAdd(&cur[d], 1);
  if ((unsigned)slot < NNZT) col[slot] = s;
}

// ---- per-layer P/Q: out = relu?(acc*P + Q); P carries the fp8-GEMM /64 fold ----
__global__ void k_pq(const float* g, const float* be, const float* m, const float* v,
                     const float* __restrict__ b, int has_bn,
                     float* __restrict__ P, float* __restrict__ Q){
  int j = threadIdx.x;
  if (has_bn){
    float A = g[j] * rsqrtf(v[j] + 1e-5f);
    P[j] = A * 0.015625f;                            // A/64
    Q[j] = (b[j] - m[j]) * A + be[j];
  } else {
    P[j] = 0.015625f;                                // 1/64
    Q[j] = b[j];
  }
}

// ---- alpha: [als|ald] = x8 @ Vt^T via one MFMA wave per 16 nodes (r11-proven) ----
__global__ void __launch_bounds__(256) k_alpha8(const unsigned char* __restrict__ x8,
    const unsigned short* __restrict__ vt,
    float* __restrict__ als, float* __restrict__ ald){
  int tile = blockIdx.x * 4 + (threadIdx.x >> 6);
  if (tile >= NN / 16) return;                       // 6250 exact
  int lane = threadIdx.x & 63;
  int ri = lane & 15, kg = lane >> 4;
  size_t m0 = (size_t)tile * 16;
  const unsigned char* arow = x8 + (m0 + ri) * DIM;  // row ri of the 16-node tile
  const int4* B = (const int4*)vt;                   // [16][256] bf16
  f32x4 acc = {0.f, 0.f, 0.f, 0.f};
  #pragma unroll
  for (int ks = 0; ks < 8; ++ks){
    uint2 raw = *(const uint2*)(arow + (ks * 4 + kg) * 8);
    v8bf av = fp8x8_to_bf16(raw);
    v8bf bv = __builtin_bit_cast(v8bf, B[ri * 32 + ks * 4 + kg]);
    acc = __builtin_amdgcn_mfma_f32_16x16x32_bf16(av, bv, acc, 0, 0, 0);
  }
  #pragma unroll
  for (int r = 0; r < 4; ++r){
    size_t m = m0 + kg * 4 + r;
    if (ri < 8) als[m * 8 + ri] = acc[r];
    else        ald[m * 8 + (ri - 8)] = acc[r];
  }
}

// ---- aggregation v3: lane = (dim-pos p = lane&31 owning dims p*8..+7,
// head-group g = lane>>5 owning heads g*4..+3). Phase A unchanged from r14
// (e=lane>>3, h=lane&7 computes w once per (edge,head), LDS broadcast).
// Phase B per edge: 1 uint2 x-load + 4 cvt_pk + 1 float4 w-read + 16 pk_fma.
__global__ void __launch_bounds__(256) k_aggregate_x8(const unsigned char* __restrict__ x8,
    const float* __restrict__ als, const float* __restrict__ ald,
    const int* __restrict__ rp, const int* __restrict__ col,
    unsigned char* __restrict__ z8){
  __shared__ __align__(16) float wbuf[4][8][8];      // [wave][edge][head]
  __shared__ __align__(16) int   sbuf[4][8];
  __shared__ __align__(16) float dbuf[4][8];
  int wid = threadIdx.x >> 6;
  int lane = threadIdx.x & 63;
  int n = blockIdx.x * 4 + wid;                      // 100000 exact
  int eh_e = lane >> 3, eh_h = lane & 7;
  int p = lane & 31, g = lane >> 5;
  int start = rp[n], end = rp[n + 1];
  if (start < 0) start = 0;
  if (end > NNZT) end = NNZT;
  if (end < start) end = start;
  float aldv = ald[(size_t)n * 8 + eh_h];
  const unsigned char* xlane = x8 + p * 8;

  f32x2 acc2[4][4];                                  // [local head][dim pair]
  #pragma unroll
  for (int hh = 0; hh < 4; ++hh)
    #pragma unroll
    for (int q = 0; q < 4; ++q) acc2[hh][q] = (f32x2){0.f, 0.f};

  float denp = 0.f;
  for (int c = start; c < end; c += 8){
    // phase A: one w per (edge,head)
    int e = c + eh_e;
    float w = 0.f; int src = n;
    if (e < end){
      src = col[e];
      if ((unsigned)src >= NN) src = n;
      w = __expf(lrelu(als[(size_t)src * 8 + eh_h] + aldv));
    }
    wbuf[wid][eh_e][eh_h] = w;
    if (eh_h == 0) sbuf[wid][eh_e] = src;
    denp += w;
    asm volatile("" ::: "memory");                   // order LDS write -> read (in-order per wave)
    int4 s03 = *(const int4*)&sbuf[wid][0];
    int4 s47 = *(const int4*)&sbuf[wid][4];
    int ss[8] = {s03.x, s03.y, s03.z, s03.w, s47.x, s47.y, s47.z, s47.w};
    // phase B: 8 edges, independent loads (8-deep MLP)
    #pragma unroll
    for (int j = 0; j < 8; ++j){
      uint2 xv = *(const uint2*)(xlane + (size_t)ss[j] * DIM);
      f32x2 x01 = __builtin_amdgcn_cvt_pk_f32_fp8((int)xv.x, false);
      f32x2 x23 = __builtin_amdgcn_cvt_pk_f32_fp8((int)xv.x, true);
      f32x2 x45 = __builtin_amdgcn_cvt_pk_f32_fp8((int)xv.y, false);
      f32x2 x67 = __builtin_amdgcn_cvt_pk_f32_fp8((int)xv.y, true);
      float4 wv = *(const float4*)&wbuf[wid][j][g * 4];
      f32x2 w0 = {wv.x, wv.x}, w1 = {wv.y, wv.y};
      f32x2 w2 = {wv.z, wv.z}, w3 = {wv.w, wv.w};
      acc2[0][0] = pkfma(x01, w0, acc2[0][0]); acc2[0][1] = pkfma(x23, w0, acc2[0][1]);
      acc2[0][2] = pkfma(x45, w0, acc2[0][2]); acc2[0][3] = pkfma(x67, w0, acc2[0][3]);
      acc2[1][0] = pkfma(x01, w1, acc2[1][0]); acc2[1][1] = pkfma(x23, w1, acc2[1][1]);
      acc2[1][2] = pkfma(x45, w1, acc2[1][2]); acc2[1][3] = pkfma(x67, w1, acc2[1][3]);
      acc2[2][0] = pkfma(x01, w2, acc2[2][0]); acc2[2][1] = pkfma(x23, w2, acc2[2][1]);
      acc2[2][2] = pkfma(x45, w2, acc2[2][2]); acc2[2][3] = pkfma(x67, w2, acc2[2][3]);
      acc2[3][0] = pkfma(x01, w3, acc2[3][0]); acc2[3][1] = pkfma(x23, w3, acc2[3][1]);
      acc2[3][2] = pkfma(x45, w3, acc2[3][2]); acc2[3][3] = pkfma(x67, w3, acc2[3][3]);
    }
  }
  // den: reduce over edge-slot lanes (bits 3,4,5), invert, broadcast via LDS
  denp += __shfl_xor(denp, 8, 64);
  denp += __shfl_xor(denp, 16, 64);
  denp += __shfl_xor(denp, 32, 64);
  if (eh_e == 0) dbuf[wid][eh_h] = 1.0f / denp;      // lanes 0..7
  asm volatile("" ::: "memory");
  float4 rv = *(const float4*)&dbuf[wid][g * 4];
  float rr[4] = {rv.x, rv.y, rv.z, rv.w};
  unsigned char* zrow = z8 + (size_t)n * WCOLS + p * 8;
  #pragma unroll
  for (int hh = 0; hh < 4; ++hh){
    int head = g * 4 + hh;
    float v0 = acc2[hh][0][0] * rr[hh], v1 = acc2[hh][0][1] * rr[hh];
    float v2 = acc2[hh][1][0] * rr[hh], v3 = acc2[hh][1][1] * rr[hh];
    float v4 = acc2[hh][2][0] * rr[hh], v5 = acc2[hh][2][1] * rr[hh];
    float v6 = acc2[hh][3][0] * rr[hh], v7 = acc2[hh][3][1] * rr[hh];
    int d0 = __builtin_amdgcn_cvt_pk_fp8_f32(v0, v1, 0, false);
    d0 = __builtin_amdgcn_cvt_pk_fp8_f32(v2, v3, d0, true);
    int d1 = __builtin_amdgcn_cvt_pk_fp8_f32(v4, v5, 0, false);
    d1 = __builtin_amdgcn_cvt_pk_fp8_f32(v6, v7, d1, true);
    uint2 pk2 = make_uint2((unsigned)d0, (unsigned)d1);
    *(uint2*)(zrow + head * 256) = pk2;              // coalesced per head
  }
}

// ---- big GEMM (EXACT r14/r15-proven fp8 + double-buffered gl_lds pipeline) ----
__global__ void __launch_bounds__(512) k_gemm2(const unsigned char* __restrict__ z8,
    const unsigned char* __restrict__ bt8,
    const float* __restrict__ Pb, const float* __restrict__ Qb,
    unsigned char* __restrict__ x8out, float* __restrict__ fout, int last){
  __shared__ __align__(16) unsigned char sA[2][128 * 64];   // 2 x 8 KB
  __shared__ __align__(16) unsigned char sB[2][256 * 64];   // 2 x 16 KB
  int tid = threadIdx.x;
  int w = tid >> 6, lane = tid & 63;
  int wr = w >> 2, wc = w & 3;
  int ri = lane & 15, kg = lane >> 4;
  int m0 = blockIdx.x * 128;

  // staging source addresses (16B units, swizzled on the global side)
  int rowU = tid >> 2;                         // 0..127
  int gblk = (tid & 3) ^ ((tid >> 3) & 3);     // = (u&3) ^ ((row>>1)&3)
  int rA = imin(m0 + rowU, NN - 1);
  const unsigned char* gA  = z8  + (size_t)rA * WCOLS + gblk * 16;
  const unsigned char* gB0 = bt8 + (size_t)rowU * WCOLS + gblk * 16;          // rows 0..127
  const unsigned char* gB1 = bt8 + (size_t)(128 + rowU) * WCOLS + gblk * 16;  // rows 128..255
  int woff = w << 10;

  f32x4 acc[4][4];
  #pragma unroll
  for (int i = 0; i < 4; ++i)
    #pragma unroll
    for (int j = 0; j < 4; ++j) acc[i][j] = (f32x4){0.f, 0.f, 0.f, 0.f};

  // prologue: stage t=0 into buffer 0
  gl_lds16(gA,  &sA[0][woff]);
  gl_lds16(gB0, &sB[0][woff]);
  gl_lds16(gB1, &sB[0][8192 + woff]);

  int cur = 0;
  for (int t = 0; t < 32; ++t){
    __syncthreads();                           // buf[cur] ready, buf[cur^1] free
    if (t < 31){
      int kn = (t + 1) * 64;
      gl_lds16(gA + kn,  &sA[cur ^ 1][woff]);
      gl_lds16(gB0 + kn, &sB[cur ^ 1][woff]);
      gl_lds16(gB1 + kn, &sB[cur ^ 1][8192 + woff]);
    }
    const unsigned char* a_base = &sA[cur][0];
    const unsigned char* b_base = &sB[cur][0];
    long long aLo[4], aHi[4], bLo[4], bHi[4];
    #pragma unroll
    for (int ai = 0; ai < 4; ++ai){
      int r = wr * 64 + ai * 16 + ri;
      int c = kg ^ ((r >> 1) & 3);
      uint4 av = *(const uint4*)(a_base + r * 64 + c * 16);
      aLo[ai] = mk64(av.x, av.y);
      aHi[ai] = mk64(av.z, av.w);
    }
    #pragma unroll
    for (int bj = 0; bj < 4; ++bj){
      int r = wc * 64 + bj * 16 + ri;
      int c = kg ^ ((r >> 1) & 3);
      uint4 bv = *(const uint4*)(b_base + r * 64 + c * 16);
      bLo[bj] = mk64(bv.x, bv.y);
      bHi[bj] = mk64(bv.z, bv.w);
    }
    #pragma unroll
    for (int ai = 0; ai < 4; ++ai)
      #pragma unroll
      for (int bj = 0; bj < 4; ++bj){
        acc[ai][bj] = __builtin_amdgcn_mfma_f32_16x16x32_fp8_fp8(aLo[ai], bLo[bj], acc[ai][bj], 0, 0, 0);
        acc[ai][bj] = __builtin_amdgcn_mfma_f32_16x16x32_fp8_fp8(aHi[ai], bHi[bj], acc[ai][bj], 0, 0, 0);
      }
    cur ^= 1;
  }

  // epilogue: C[m0 + wr*64 + ai*16 + kg*4 + r][wc*64 + bj*16 + ri]
  #pragma unroll
  for (int bj = 0; bj < 4; ++bj){
    int colj = wc * 64 + bj * 16 + ri;
    float p = Pb[colj], q = Qb[colj];
    #pragma unroll
    for (int ai = 0; ai < 4; ++ai){
      #pragma unroll
      for (int r = 0; r < 4; ++r){
        int row = m0 + wr * 64 + ai * 16 + kg * 4 + r;
        if (row < NN){
          float v = acc[ai][bj][r] * p + q;
          if (!last){
            v = fmaxf(v, 0.f);
            x8out[(size_t)row * DIM + colj] = f2fp8(v);
          } else {
            fout[(size_t)row * DIM + colj] = v;
          }
        }
      }
    }
  }
}

// ---- doc GEMM split-K (r15-proven) ----
__global__ void __launch_bounds__(256) k_doc_part(const float* __restrict__ dd,
    const float* __restrict__ dw, float* __restrict__ part){
  int bid = blockIdx.x;
  int r = bid >> 2, q = bid & 3;
  int j = threadIdx.x;
  const float* drow = dd + (size_t)r * 3072 + q * 768;
  const float* wcol = dw + (size_t)q * 768 * 256 + j;
  float acc = 0.f;
  #pragma unroll 8
  for (int k = 0; k < 768; ++k)
    acc = fmaf(drow[k], wcol[(size_t)k * 256], acc);
  part[(size_t)bid * 256 + j] = acc;
}
__global__ void __launch_bounds__(256) k_doc_red(const float* __restrict__ part,
    const float* __restrict__ db, float* __restrict__ out){
  int r = blockIdx.x, j = threadIdx.x;
  size_t base = (size_t)r * 4 * 256 + j;
  float v = part[base] + part[base + 256] + part[base + 512] + part[base + 768] + db[j];
  out[(size_t)NN * DIM + (size_t)r * 256 + j] = v;
}

extern "C" void kernel_launch(void* const* d_in, const int* in_sizes, int n_in,
                              void* d_out, int out_size, void* d_ws, size_t ws_size,
                              hipStream_t stream) {
  (void)in_sizes; (void)n_in; (void)out_size; (void)ws_size;
  const float* x      = (const float*)d_in[0];
  const int*   ei     = (const int*)d_in[1];
  const float* doc    = (const float*)d_in[2];
  const float* W[3]   = {(const float*)d_in[3], (const float*)d_in[7], (const float*)d_in[11]};
  const float* as_[3] = {(const float*)d_in[4], (const float*)d_in[8], (const float*)d_in[12]};
  const float* ad_[3] = {(const float*)d_in[5], (const float*)d_in[9], (const float*)d_in[13]};
  const float* b_[3]  = {(const float*)d_in[6], (const float*)d_in[10], (const float*)d_in[14]};
  const float* bng[2] = {(const float*)d_in[15], (const float*)d_in[19]};
  const float* bnb[2] = {(const float*)d_in[16], (const float*)d_in[20]};
  const float* bnm[2] = {(const float*)d_in[17], (const float*)d_in[21]};
  const float* bnv[2] = {(const float*)d_in[18], (const float*)d_in[22]};
  const float* docW   = (const float*)d_in[23];
  const float* docB   = (const float*)d_in[24];
  float* out = (float*)d_out;

  char* ws = (char*)d_ws;
  // EXACT r15-proven layout (ends 254,659,200 < 279,947,840 proven bound).
  unsigned char*  x8   = (unsigned char*)(ws + 0);             //  25,600,000
  unsigned char*  z8   = (unsigned char*)(ws + 25600000);      // 204,800,000
  float* als           = (float*)(ws + 230400000);             //   3,200,000
  float* ald           = (float*)(ws + 233600000);             //   3,200,000
  unsigned char* bt8   = (unsigned char*)(ws + 236800000);     //   1,572,864 used (3 x 512 KiB)
  int* rp              = (int*)(ws + 239945728);               //     400,064
  int* deg             = (int*)(ws + 240345792);               //     400,000
  int* cur             = (int*)(ws + 240745792);               //     400,000
  int* colb            = (int*)(ws + 241145792);               //  13,200,000
  unsigned short* vt   = (unsigned short*)(ws + 254345792);    //      24,576 (3 x 8 KiB)
  float* Pb            = (float*)(ws + 254394944);             //       1,024
  float* Qb            = (float*)(ws + 254395968);             //       1,024
  float* docpart       = (float*)(ws + 254397056);             //     262,144 -> end 254,659,200

  // input prep
  k_cast_x8<<<25000, 256, 0, stream>>>(x, x8);
  for (int L = 0; L < 3; ++L){
    k_make_waggt8<<<2048, 256, 0, stream>>>(W[L], bt8 + (size_t)L * 524288);
    k_make_vt<<<8, 256, 0, stream>>>(W[L], as_[L], ad_[L], vt + (size_t)L * 4096);
  }

  // CSR (shared by all 3 layers); deg/cur strictly distinct buffers
  k_zero_col<<<12891, 256, 0, stream>>>(colb);
  k_deg_init<<<391, 256, 0, stream>>>(deg);
  k_hist<<<12500, 256, 0, stream>>>(ei, deg);
  k_scan<<<1, 1024, 0, stream>>>(deg, rp, cur);
  k_fill_self<<<391, 256, 0, stream>>>(cur, colb);
  k_fill_edge<<<12500, 256, 0, stream>>>(ei, cur, colb);

  // doc branch (split-K, deterministic)
  k_doc_part<<<256, 256, 0, stream>>>(doc, docW, docpart);
  k_doc_red<<<64, 256, 0, stream>>>(docpart, docB, out);

  // layers
  for (int L = 0; L < 3; ++L){
    int has_bn = (L < 2) ? 1 : 0;
    k_pq<<<1, 256, 0, stream>>>(has_bn ? bng[L] : nullptr, has_bn ? bnb[L] : nullptr,
                                has_bn ? bnm[L] : nullptr, has_bn ? bnv[L] : nullptr,
                                b_[L], has_bn, Pb, Qb);
    k_alpha8<<<1563, 256, 0, stream>>>(x8, vt + (size_t)L * 4096, als, ald);
    k_aggregate_x8<<<25000, 256, 0, stream>>>(x8, als, ald, rp, colb, z8);
    k_gemm2<<<782, 512, 0, stream>>>(z8, bt8 + (size_t)L * 524288, Pb, Qb,
                                     x8, out, (L == 2) ? 1 : 0);
  }
}

// Round 17
// 1855.731 us; speedup vs baseline: 1.0793x; 1.0793x over previous
//
#include <hip/hip_runtime.h>
#include <stdint.h>

#define NN 100000
#define NE 3200000
#define NNZT (NE + NN)
#define DIM 256
#define WCOLS 2048

typedef __bf16 v8bf __attribute__((ext_vector_type(8)));
typedef float f32x4 __attribute__((ext_vector_type(4)));
typedef float f32x2 __attribute__((ext_vector_type(2)));
typedef _Float16 h2 __attribute__((ext_vector_type(2)));

__device__ __forceinline__ unsigned f2bfu(float f){
  unsigned u = __builtin_bit_cast(unsigned, f);
  return (u + 0x7FFFu + ((u >> 16) & 1u)) >> 16;
}
__device__ __forceinline__ float lrelu(float x){ return fmaxf(x, 0.2f * x); }
__device__ __forceinline__ int imin(int a, int b){ return a < b ? a : b; }
__device__ __forceinline__ unsigned char f2fp8(float f){
  return (unsigned char)(__builtin_amdgcn_cvt_pk_fp8_f32(f, f, 0, false) & 0xff);
}
// packed f16 FMA: one 32-bit VGPR = 2 halves -> 2 MACs per single issue
__device__ __forceinline__ unsigned pkfma16(unsigned a, unsigned b, unsigned c){
  unsigned d;
  asm("v_pk_fma_f16 %0, %1, %2, %3" : "=v"(d) : "v"(a), "v"(b), "v"(c));
  return d;
}
__device__ __forceinline__ unsigned pk16(float a, float b){
  return __builtin_bit_cast(unsigned, __builtin_amdgcn_cvt_pkrtz(a, b));
}
// 8 fp8 bytes (uint2) -> v8bf (8 bf16), element order preserved
__device__ __forceinline__ v8bf fp8x8_to_bf16(uint2 raw){
  f32x2 f01 = __builtin_amdgcn_cvt_pk_f32_fp8((int)raw.x, false);
  f32x2 f23 = __builtin_amdgcn_cvt_pk_f32_fp8((int)raw.x, true);
  f32x2 f45 = __builtin_amdgcn_cvt_pk_f32_fp8((int)raw.y, false);
  f32x2 f67 = __builtin_amdgcn_cvt_pk_f32_fp8((int)raw.y, true);
  v8bf r;
  r[0] = (__bf16)f01[0]; r[1] = (__bf16)f01[1];
  r[2] = (__bf16)f23[0]; r[3] = (__bf16)f23[1];
  r[4] = (__bf16)f45[0]; r[5] = (__bf16)f45[1];
  r[6] = (__bf16)f67[0]; r[7] = (__bf16)f67[1];
  return r;
}
// async global -> LDS, 16B per lane; LDS dest is wave-uniform base + lane*16
__device__ __forceinline__ void gl_lds16(const void* g, void* l){
  __builtin_amdgcn_global_load_lds(
      (const __attribute__((address_space(1))) void*)g,
      (__attribute__((address_space(3))) void*)l, 16, 0, 0);
}
__device__ __forceinline__ long long mk64(unsigned lo, unsigned hi){
  return (long long)(((unsigned long long)hi << 32) | lo);
}

// ---- cast x fp32 -> fp8 (4 elems/thread) ----
__global__ void k_cast_x8(const float* __restrict__ x, unsigned char* __restrict__ x8){
  int t = blockIdx.x * 256 + threadIdx.x;           // 6.4M threads exact
  float4 v = ((const float4*)x)[t];
  int lo = __builtin_amdgcn_cvt_pk_fp8_f32(v.x, v.y, 0, false);
  int both = __builtin_amdgcn_cvt_pk_fp8_f32(v.z, v.w, lo, true);
  ((int*)x8)[t] = both;
}

// ---- WaggT8[j][h*256+d] = fp8( W[d][h*256+j] * 8 )  ([256][2048] fp8) ----
__global__ void k_make_waggt8(const float* __restrict__ W, unsigned char* __restrict__ bt8){
  int t = blockIdx.x * 256 + threadIdx.x;           // 524288
  int d = t >> 11, c = t & 2047;                    // W flat index = d*2048 + c
  bt8[(size_t)(c & 255) * WCOLS + (c >> 8) * 256 + d] = f2fp8(W[t] * 8.0f);
}

// ---- Vt[h][k] = sum_d W[k][h*256+d]*a_s[h][d]; Vt[8+h][k] same with a_d (bf16) ----
__global__ void k_make_vt(const float* __restrict__ W, const float* __restrict__ as_,
                          const float* __restrict__ ad_, unsigned short* __restrict__ vt){
  int h = blockIdx.x, k = threadIdx.x;              // 8 x 256
  const float* wr = W + (size_t)k * WCOLS + h * 256;
  const float* a1 = as_ + h * 256;
  const float* a2 = ad_ + h * 256;
  float ss = 0.f, sd = 0.f;
  for (int d = 0; d < 256; ++d){ float wv = wr[d]; ss += wv * a1[d]; sd += wv * a2[d]; }
  vt[h * 256 + k] = (unsigned short)f2bfu(ss);
  vt[(8 + h) * 256 + k] = (unsigned short)f2bfu(sd);
}

// ---- CSR build (structure identical to all PASSING kernels) ----
__global__ void k_zero_col(int* __restrict__ col){
  int t = blockIdx.x * 256 + threadIdx.x;
  if (t < NNZT) col[t] = 0;
}
__global__ void k_deg_init(int* __restrict__ deg){
  int t = blockIdx.x * 256 + threadIdx.x;
  if (t < NN) deg[t] = 1;                            // self-loop
}
__global__ void k_hist(const int* __restrict__ ei, int* __restrict__ deg){
  int t = blockIdx.x * 256 + threadIdx.x;            // NE threads exact
  int d = ei[NE + t];
  if ((unsigned)d < NN) atomicAdd(&deg[d], 1);
}
__global__ void __launch_bounds__(1024) k_scan(const int* __restrict__ deg,
                                               int* __restrict__ rp, int* cur){
  __shared__ int ps[1024];
  int t = threadIdx.x;
  int lo = t * 98;
  int hi = lo + 98; if (hi > NN) hi = NN; if (lo > NN) lo = NN;
  int s = 0;
  for (int i = lo; i < hi; ++i) s += deg[i];
  ps[t] = s;
  __syncthreads();
  if (t == 0){
    int run = 0;
    for (int i = 0; i < 1024; ++i){ int v = ps[i]; ps[i] = run; run += v; }
    rp[NN] = run;
  }
  __syncthreads();
  int run = ps[t];
  for (int i = lo; i < hi; ++i){
    int dv = deg[i];
    rp[i] = run; cur[i] = run;
    run += dv;
  }
}
__global__ void k_fill_self(int* __restrict__ cur, int* __restrict__ col){
  int t = blockIdx.x * 256 + threadIdx.x;
  if (t < NN){
    int s = atomicAdd(&cur[t], 1);
    if ((unsigned)s < NNZT) col[s] = t;
  }
}
__global__ void k_fill_edge(const int* __restrict__ ei, int* __restrict__ cur, int* __restrict__ col){
  int t = blockIdx.x * 256 + threadIdx.x;
  int s = ei[t], d = ei[NE + t];
  if ((unsigned)d >= NN) return;                     // matches k_hist guard
  if ((unsigned)s >= NN) s = d;
  int slot = atomicAdd(&cur[d], 1);
  if ((unsigned)slot < NNZT) col[slot] = s;
}

// ---- per-layer P/Q: out = relu?(acc*P + Q); P carries the fp8-GEMM /64 fold ----
__global__ void k_pq(const float* g, const float* be, const float* m, const float* v,
                     const float* __restrict__ b, int has_bn,
                     float* __restrict__ P, float* __restrict__ Q){
  int j = threadIdx.x;
  if (has_bn){
    float A = g[j] * rsqrtf(v[j] + 1e-5f);
    P[j] = A * 0.015625f;                            // A/64
    Q[j] = (b[j] - m[j]) * A + be[j];
  } else {
    P[j] = 0.015625f;                                // 1/64
    Q[j] = b[j];
  }
}

// ---- alpha: [als|ald] = x8 @ Vt^T via one MFMA wave per 16 nodes (r11-proven) ----
__global__ void __launch_bounds__(256) k_alpha8(const unsigned char* __restrict__ x8,
    const unsigned short* __restrict__ vt,
    float* __restrict__ als, float* __restrict__ ald){
  int tile = blockIdx.x * 4 + (threadIdx.x >> 6);
  if (tile >= NN / 16) return;                       // 6250 exact
  int lane = threadIdx.x & 63;
  int ri = lane & 15, kg = lane >> 4;
  size_t m0 = (size_t)tile * 16;
  const unsigned char* arow = x8 + (m0 + ri) * DIM;  // row ri of the 16-node tile
  const int4* B = (const int4*)vt;                   // [16][256] bf16
  f32x4 acc = {0.f, 0.f, 0.f, 0.f};
  #pragma unroll
  for (int ks = 0; ks < 8; ++ks){
    uint2 raw = *(const uint2*)(arow + (ks * 4 + kg) * 8);
    v8bf av = fp8x8_to_bf16(raw);
    v8bf bv = __builtin_bit_cast(v8bf, B[ri * 32 + ks * 4 + kg]);
    acc = __builtin_amdgcn_mfma_f32_16x16x32_bf16(av, bv, acc, 0, 0, 0);
  }
  #pragma unroll
  for (int r = 0; r < 4; ++r){
    size_t m = m0 + kg * 4 + r;
    if (ri < 8) als[m * 8 + ri] = acc[r];
    else        ald[m * 8 + (ri - 8)] = acc[r];
  }
}

// ---- aggregation: r14-proven structure (lane owns dims lane*4..+3, all 8
// heads; phase A computes w once per (edge,head), LDS broadcast) with
// PACKED-F16 accumulation: w pre-packed (w,w) f16 in LDS; per edge:
// 1 dword x-load + 2 cvt_pk_f32_fp8 + 2 cvt_pkrtz + 2 uint4 LDS reads +
// 16 v_pk_fma_f16 (2 MACs/issue -> halves the 32-FMA VALU cost).
__global__ void __launch_bounds__(256) k_aggregate_x8(const unsigned char* __restrict__ x8,
    const float* __restrict__ als, const float* __restrict__ ald,
    const int* __restrict__ rp, const int* __restrict__ col,
    unsigned char* __restrict__ z8){
  __shared__ __align__(16) unsigned wbuf[4][8][8];   // [wave][edge][head] packed (w,w) f16
  __shared__ __align__(16) int   sbuf[4][8];
  __shared__ __align__(16) float dbuf[4][8];
  int wid = threadIdx.x >> 6;
  int lane = threadIdx.x & 63;
  int n = blockIdx.x * 4 + wid;                      // 100000 exact
  int eh_e = lane >> 3, eh_h = lane & 7;
  int start = rp[n], end = rp[n + 1];
  if (start < 0) start = 0;
  if (end > NNZT) end = NNZT;
  if (end < start) end = start;
  float aldv = ald[(size_t)n * 8 + eh_h];
  const unsigned char* xlane = x8 + lane * 4;

  unsigned acc01[8], acc23[8];                       // packed f16: dims {0,1} and {2,3} per head
  #pragma unroll
  for (int h = 0; h < 8; ++h){ acc01[h] = 0u; acc23[h] = 0u; }

  float denp = 0.f;
  for (int c = start; c < end; c += 8){
    // phase A: one w per (edge,head), packed f16 into LDS
    int e = c + eh_e;
    float w = 0.f; int src = n;
    if (e < end){
      src = col[e];
      if ((unsigned)src >= NN) src = n;
      w = __expf(lrelu(als[(size_t)src * 8 + eh_h] + aldv));
    }
    wbuf[wid][eh_e][eh_h] = pk16(w, w);
    if (eh_h == 0) sbuf[wid][eh_e] = src;
    denp += w;
    asm volatile("" ::: "memory");                   // order LDS write -> read (in-order per wave)
    int4 s03 = *(const int4*)&sbuf[wid][0];
    int4 s47 = *(const int4*)&sbuf[wid][4];
    int ss[8] = {s03.x, s03.y, s03.z, s03.w, s47.x, s47.y, s47.z, s47.w};
    // phase B: 8 edges, independent loads (8-deep MLP)
    #pragma unroll
    for (int j = 0; j < 8; ++j){
      unsigned xd = *(const unsigned*)(xlane + (size_t)ss[j] * DIM);
      f32x2 x01 = __builtin_amdgcn_cvt_pk_f32_fp8((int)xd, false);
      f32x2 x23 = __builtin_amdgcn_cvt_pk_f32_fp8((int)xd, true);
      unsigned xh01 = pk16(x01[0], x01[1]);
      unsigned xh23 = pk16(x23[0], x23[1]);
      uint4 w0 = *(const uint4*)&wbuf[wid][j][0];
      uint4 w1 = *(const uint4*)&wbuf[wid][j][4];
      acc01[0] = pkfma16(xh01, w0.x, acc01[0]); acc23[0] = pkfma16(xh23, w0.x, acc23[0]);
      acc01[1] = pkfma16(xh01, w0.y, acc01[1]); acc23[1] = pkfma16(xh23, w0.y, acc23[1]);
      acc01[2] = pkfma16(xh01, w0.z, acc01[2]); acc23[2] = pkfma16(xh23, w0.z, acc23[2]);
      acc01[3] = pkfma16(xh01, w0.w, acc01[3]); acc23[3] = pkfma16(xh23, w0.w, acc23[3]);
      acc01[4] = pkfma16(xh01, w1.x, acc01[4]); acc23[4] = pkfma16(xh23, w1.x, acc23[4]);
      acc01[5] = pkfma16(xh01, w1.y, acc01[5]); acc23[5] = pkfma16(xh23, w1.y, acc23[5]);
      acc01[6] = pkfma16(xh01, w1.z, acc01[6]); acc23[6] = pkfma16(xh23, w1.z, acc23[6]);
      acc01[7] = pkfma16(xh01, w1.w, acc01[7]); acc23[7] = pkfma16(xh23, w1.w, acc23[7]);
    }
  }
  // den: reduce over edge-slot lanes (bits 3,4,5), invert, broadcast via LDS
  denp += __shfl_xor(denp, 8, 64);
  denp += __shfl_xor(denp, 16, 64);
  denp += __shfl_xor(denp, 32, 64);
  if (eh_e == 0) dbuf[wid][eh_h] = 1.0f / denp;      // lanes 0..7
  asm volatile("" ::: "memory");
  float4 rA = *(const float4*)&dbuf[wid][0];
  float4 rB = *(const float4*)&dbuf[wid][4];
  float rr[8] = {rA.x, rA.y, rA.z, rA.w, rB.x, rB.y, rB.z, rB.w};
  unsigned char* zrow = z8 + (size_t)n * WCOLS + lane * 4;
  #pragma unroll
  for (int h = 0; h < 8; ++h){
    h2 p01 = __builtin_bit_cast(h2, acc01[h]);
    h2 p23 = __builtin_bit_cast(h2, acc23[h]);
    float v0 = (float)p01[0] * rr[h], v1 = (float)p01[1] * rr[h];
    float v2 = (float)p23[0] * rr[h], v3 = (float)p23[1] * rr[h];
    int lo = __builtin_amdgcn_cvt_pk_fp8_f32(v0, v1, 0, false);
    int pk = __builtin_amdgcn_cvt_pk_fp8_f32(v2, v3, lo, true);
    *(unsigned*)(zrow + h * 256) = (unsigned)pk;     // coalesced per head
  }
}

// ---- big GEMM (EXACT r14/r15-proven fp8 + double-buffered gl_lds pipeline) ----
__global__ void __launch_bounds__(512) k_gemm2(const unsigned char* __restrict__ z8,
    const unsigned char* __restrict__ bt8,
    const float* __restrict__ Pb, const float* __restrict__ Qb,
    unsigned char* __restrict__ x8out, float* __restrict__ fout, int last){
  __shared__ __align__(16) unsigned char sA[2][128 * 64];   // 2 x 8 KB
  __shared__ __align__(16) unsigned char sB[2][256 * 64];   // 2 x 16 KB
  int tid = threadIdx.x;
  int w = tid >> 6, lane = tid & 63;
  int wr = w >> 2, wc = w & 3;
  int ri = lane & 15, kg = lane >> 4;
  int m0 = blockIdx.x * 128;

  // staging source addresses (16B units, swizzled on the global side)
  int rowU = tid >> 2;                         // 0..127
  int gblk = (tid & 3) ^ ((tid >> 3) & 3);     // = (u&3) ^ ((row>>1)&3)
  int rA = imin(m0 + rowU, NN - 1);
  const unsigned char* gA  = z8  + (size_t)rA * WCOLS + gblk * 16;
  const unsigned char* gB0 = bt8 + (size_t)rowU * WCOLS + gblk * 16;          // rows 0..127
  const unsigned char* gB1 = bt8 + (size_t)(128 + rowU) * WCOLS + gblk * 16;  // rows 128..255
  int woff = w << 10;

  f32x4 acc[4][4];
  #pragma unroll
  for (int i = 0; i < 4; ++i)
    #pragma unroll
    for (int j = 0; j < 4; ++j) acc[i][j] = (f32x4){0.f, 0.f, 0.f, 0.f};

  // prologue: stage t=0 into buffer 0
  gl_lds16(gA,  &sA[0][woff]);
  gl_lds16(gB0, &sB[0][woff]);
  gl_lds16(gB1, &sB[0][8192 + woff]);

  int cur = 0;
  for (int t = 0; t < 32; ++t){
    __syncthreads();                           // buf[cur] ready, buf[cur^1] free
    if (t < 31){
      int kn = (t + 1) * 64;
      gl_lds16(gA + kn,  &sA[cur ^ 1][woff]);
      gl_lds16(gB0 + kn, &sB[cur ^ 1][woff]);
      gl_lds16(gB1 + kn, &sB[cur ^ 1][8192 + woff]);
    }
    const unsigned char* a_base = &sA[cur][0];
    const unsigned char* b_base = &sB[cur][0];
    long long aLo[4], aHi[4], bLo[4], bHi[4];
    #pragma unroll
    for (int ai = 0; ai < 4; ++ai){
      int r = wr * 64 + ai * 16 + ri;
      int c = kg ^ ((r >> 1) & 3);
      uint4 av = *(const uint4*)(a_base + r * 64 + c * 16);
      aLo[ai] = mk64(av.x, av.y);
      aHi[ai] = mk64(av.z, av.w);
    }
    #pragma unroll
    for (int bj = 0; bj < 4; ++bj){
      int r = wc * 64 + bj * 16 + ri;
      int c = kg ^ ((r >> 1) & 3);
      uint4 bv = *(const uint4*)(b_base + r * 64 + c * 16);
      bLo[bj] = mk64(bv.x, bv.y);
      bHi[bj] = mk64(bv.z, bv.w);
    }
    #pragma unroll
    for (int ai = 0; ai < 4; ++ai)
      #pragma unroll
      for (int bj = 0; bj < 4; ++bj){
        acc[ai][bj] = __builtin_amdgcn_mfma_f32_16x16x32_fp8_fp8(aLo[ai], bLo[bj], acc[ai][bj], 0, 0, 0);
        acc[ai][bj] = __builtin_amdgcn_mfma_f32_16x16x32_fp8_fp8(aHi[ai], bHi[bj], acc[ai][bj], 0, 0, 0);
      }
    cur ^= 1;
  }

  // epilogue: C[m0 + wr*64 + ai*16 + kg*4 + r][wc*64 + bj*16 + ri]
  #pragma unroll
  for (int bj = 0; bj < 4; ++bj){
    int colj = wc * 64 + bj * 16 + ri;
    float p = Pb[colj], q = Qb[colj];
    #pragma unroll
    for (int ai = 0; ai < 4; ++ai){
      #pragma unroll
      for (int r = 0; r < 4; ++r){
        int row = m0 + wr * 64 + ai * 16 + kg * 4 + r;
        if (row < NN){
          float v = acc[ai][bj][r] * p + q;
          if (!last){
            v = fmaxf(v, 0.f);
            x8out[(size_t)row * DIM + colj] = f2fp8(v);
          } else {
            fout[(size_t)row * DIM + colj] = v;
          }
        }
      }
    }
  }
}

// ---- doc GEMM split-K (r15-proven) ----
__global__ void __launch_bounds__(256) k_doc_part(const float* __restrict__ dd,
    const float* __restrict__ dw, float* __restrict__ part){
  int bid = blockIdx.x;
  int r = bid >> 2, q = bid & 3;
  int j = threadIdx.x;
  const float* drow = dd + (size_t)r * 3072 + q * 768;
  const float* wcol = dw + (size_t)q * 768 * 256 + j;
  float acc = 0.f;
  #pragma unroll 8
  for (int k = 0; k < 768; ++k)
    acc = fmaf(drow[k], wcol[(size_t)k * 256], acc);
  part[(size_t)bid * 256 + j] = acc;
}
__global__ void __launch_bounds__(256) k_doc_red(const float* __restrict__ part,
    const float* __restrict__ db, float* __restrict__ out){
  int r = blockIdx.x, j = threadIdx.x;
  size_t base = (size_t)r * 4 * 256 + j;
  float v = part[base] + part[base + 256] + part[base + 512] + part[base + 768] + db[j];
  out[(size_t)NN * DIM + (size_t)r * 256 + j] = v;
}

extern "C" void kernel_launch(void* const* d_in, const int* in_sizes, int n_in,
                              void* d_out, int out_size, void* d_ws, size_t ws_size,
                              hipStream_t stream) {
  (void)in_sizes; (void)n_in; (void)out_size; (void)ws_size;
  const float* x      = (const float*)d_in[0];
  const int*   ei     = (const int*)d_in[1];
  const float* doc    = (const float*)d_in[2];
  const float* W[3]   = {(const float*)d_in[3], (const float*)d_in[7], (const float*)d_in[11]};
  const float* as_[3] = {(const float*)d_in[4], (const float*)d_in[8], (const float*)d_in[12]};
  const float* ad_[3] = {(const float*)d_in[5], (const float*)d_in[9], (const float*)d_in[13]};
  const float* b_[3]  = {(const float*)d_in[6], (const float*)d_in[10], (const float*)d_in[14]};
  const float* bng[2] = {(const float*)d_in[15], (const float*)d_in[19]};
  const float* bnb[2] = {(const float*)d_in[16], (const float*)d_in[20]};
  const float* bnm[2] = {(const float*)d_in[17], (const float*)d_in[21]};
  const float* bnv[2] = {(const float*)d_in[18], (const float*)d_in[22]};
  const float* docW   = (const float*)d_in[23];
  const float* docB   = (const float*)d_in[24];
  float* out = (float*)d_out;

  char* ws = (char*)d_ws;
  // EXACT r15-proven layout (ends 254,659,200 < 279,947,840 proven bound).
  unsigned char*  x8   = (unsigned char*)(ws + 0);             //  25,600,000
  unsigned char*  z8   = (unsigned char*)(ws + 25600000);      // 204,800,000
  float* als           = (float*)(ws + 230400000);             //   3,200,000
  float* ald           = (float*)(ws + 233600000);             //   3,200,000
  unsigned char* bt8   = (unsigned char*)(ws + 236800000);     //   1,572,864 used (3 x 512 KiB)
  int* rp              = (int*)(ws + 239945728);               //     400,064
  int* deg             = (int*)(ws + 240345792);               //     400,000
  int* cur             = (int*)(ws + 240745792);               //     400,000
  int* colb            = (int*)(ws + 241145792);               //  13,200,000
  unsigned short* vt   = (unsigned short*)(ws + 254345792);    //      24,576 (3 x 8 KiB)
  float* Pb            = (float*)(ws + 254394944);             //       1,024
  float* Qb            = (float*)(ws + 254395968);             //       1,024
  float* docpart       = (float*)(ws + 254397056);             //     262,144 -> end 254,659,200

  // input prep
  k_cast_x8<<<25000, 256, 0, stream>>>(x, x8);
  for (int L = 0; L < 3; ++L){
    k_make_waggt8<<<2048, 256, 0, stream>>>(W[L], bt8 + (size_t)L * 524288);
    k_make_vt<<<8, 256, 0, stream>>>(W[L], as_[L], ad_[L], vt + (size_t)L * 4096);
  }

  // CSR (shared by all 3 layers); deg/cur strictly distinct buffers
  k_zero_col<<<12891, 256, 0, stream>>>(colb);
  k_deg_init<<<391, 256, 0, stream>>>(deg);
  k_hist<<<12500, 256, 0, stream>>>(ei, deg);
  k_scan<<<1, 1024, 0, stream>>>(deg, rp, cur);
  k_fill_self<<<391, 256, 0, stream>>>(cur, colb);
  k_fill_edge<<<12500, 256, 0, stream>>>(ei, cur, colb);

  // doc branch (split-K, deterministic)
  k_doc_part<<<256, 256, 0, stream>>>(doc, docW, docpart);
  k_doc_red<<<64, 256, 0, stream>>>(docpart, docB, out);

  // layers
  for (int L = 0; L < 3; ++L){
    int has_bn = (L < 2) ? 1 : 0;
    k_pq<<<1, 256, 0, stream>>>(has_bn ? bng[L] : nullptr, has_bn ? bnb[L] : nullptr,
                                has_bn ? bnm[L] : nullptr, has_bn ? bnv[L] : nullptr,
                                b_[L], has_bn, Pb, Qb);
    k_alpha8<<<1563, 256, 0, stream>>>(x8, vt + (size_t)L * 4096, als, ald);
    k_aggregate_x8<<<25000, 256, 0, stream>>>(x8, als, ald, rp, colb, z8);
    k_gemm2<<<782, 512, 0, stream>>>(z8, bt8 + (size_t)L * 524288, Pb, Qb,
                                     x8, out, (L == 2) ? 1 : 0);
  }
}